// Round 1
// baseline (361.138 us; speedup 1.0000x reference)
//
#include <hip/hip_runtime.h>
#include <hip/hip_bf16.h>

// DeepSeek V4 MLA sparse attention, MI355X gfx950.
// dims
#define T_TOK 512
#define NH    64
#define HD    576
#define DVAL  512
#define NKV   8192
#define TOPK  1024
#define KT    32
#define NITER (TOPK / KT)   // 32
#define KSTEPS (HD / 32)    // 18
#define SCALE 0.041666666666666664f  // 1/24

typedef __attribute__((ext_vector_type(4))) float f32x4;
typedef __attribute__((ext_vector_type(8))) _Float16 half8;
typedef __attribute__((ext_vector_type(4))) unsigned short us4;
typedef __attribute__((ext_vector_type(8))) unsigned short us8;
typedef __attribute__((ext_vector_type(4))) int i32x4;

__device__ __forceinline__ unsigned short f2h(float x) {
    _Float16 h = (_Float16)x;
    return __builtin_bit_cast(unsigned short, h);
}

// ---- prep: kv fp32 -> fp16 in workspace (9.4 MB) ----
__global__ void cvt_kv_f16(const float* __restrict__ kv, unsigned short* __restrict__ kvb) {
    int i = blockIdx.x * 256 + threadIdx.x;          // 0 .. 589823 (NKV*HD/8 exactly)
    const f32x4* src = (const f32x4*)kv + (size_t)i * 2;
    f32x4 a = src[0];
    f32x4 b = src[1];
    us8 w;
    w[0]=f2h(a[0]); w[1]=f2h(a[1]); w[2]=f2h(a[2]); w[3]=f2h(a[3]);
    w[4]=f2h(b[0]); w[5]=f2h(b[1]); w[6]=f2h(b[2]); w[7]=f2h(b[3]);
    ((us8*)kvb)[i] = w;
}

// LDS leading dims (padded for 16B alignment + 2-way-max bank aliasing)
#define G_LD  584   // 576 + 8 fp16 pad; row = 1168 B (16B-mult, 292 words ≡ 4 mod 32)
#define GT_LD 40    // 32 + 8 pad; row = 80 B (16B-mult, 20 words ≡ 20 mod 32)
#define S_LD  36
#define P_LD  40

__global__ __launch_bounds__(512, 2) void mla_sparse_kernel(
    const float* __restrict__ q, const int* __restrict__ topk,
    const float* __restrict__ sink, const unsigned short* __restrict__ kvb,
    float* __restrict__ out)
{
    __shared__ unsigned short g[KT][G_LD];    // gathered tile, [key][d]      (37,376 B)
    __shared__ unsigned short gt[DVAL][GT_LD];// transposed,    [vcol][key]   (40,960 B)
    __shared__ float sbuf[NH][S_LD];          // raw scores                   ( 9,216 B)
    __shared__ unsigned short pbuf[NH][P_LD]; // softmaxed P (fp16)           ( 5,120 B)
    __shared__ float bias[KT];                // 0 or -inf per key slot
    __shared__ float mrun[NH], lrun[NH], arun[NH];
    // total ~93.6 KB -> 1 block/CU

    const int t    = blockIdx.x;
    const int tid  = threadIdx.x;
    const int wave = tid >> 6;
    const int lane = tid & 63;
    const int quad = lane >> 4;
    const int l16  = lane & 15;

    // sink folded into online-softmax init: m = sink[h], l = exp(sink-m) = 1
    if (tid < NH) { mrun[tid] = sink[tid]; lrun[tid] = 1.0f; }

    // S-GEMM tile assignment: wave w -> (mtile = w&3, ntile = w>>2); Q A-frags in regs
    const int mtile = wave & 3;
    const int ntile = wave >> 2;
    half8 qf[KSTEPS];   // 72 VGPRs
    {
        const float* qrow = q + ((size_t)t * NH + (mtile * 16 + l16)) * HD;
        #pragma unroll
        for (int ks = 0; ks < KSTEPS; ks++) {
            int d0 = ks * 32 + quad * 8;
            f32x4 a = *(const f32x4*)(qrow + d0);
            f32x4 b = *(const f32x4*)(qrow + d0 + 4);
            half8 h;
            h[0]=(_Float16)a[0]; h[1]=(_Float16)a[1]; h[2]=(_Float16)a[2]; h[3]=(_Float16)a[3];
            h[4]=(_Float16)b[0]; h[5]=(_Float16)b[1]; h[6]=(_Float16)b[2]; h[7]=(_Float16)b[3];
            qf[ks] = h;
        }
    }

    // PV accumulators: wave owns O[:, wave*64 .. +63]: 4 mtiles x 4 ntiles of 16x16
    f32x4 acc[4][4];
    f32x4 zero = {0.f, 0.f, 0.f, 0.f};
    #pragma unroll
    for (int mt = 0; mt < 4; mt++)
        #pragma unroll
        for (int nt = 0; nt < 4; nt++) acc[mt][nt] = zero;

    const int col0 = wave * 64;
    const int* tkrow = topk + (size_t)t * TOPK;

    __syncthreads();  // mrun/lrun init visible; also fences before first staging

    for (int it = 0; it < NITER; it++) {
        // ---- staging: gather KT fp16 rows into g (row-major) and gt (transposed) ----
        // phase A: kg = tid>>7 picks an 8-key group, dc = tid&127 picks dims [4dc,4dc+3]
        {
            int kg = tid >> 7;
            int d0 = (tid & 127) * 4;                 // 0..508
            const int* ip = tkrow + it * KT + kg * 8;
            i32x4 ra = *(const i32x4*)ip;
            i32x4 rb = *(const i32x4*)(ip + 4);
            int rows[8];
            rows[0]=ra[0]<0?0:ra[0]; rows[1]=ra[1]<0?0:ra[1];
            rows[2]=ra[2]<0?0:ra[2]; rows[3]=ra[3]<0?0:ra[3];
            rows[4]=rb[0]<0?0:rb[0]; rows[5]=rb[1]<0?0:rb[1];
            rows[6]=rb[2]<0?0:rb[2]; rows[7]=rb[3]<0?0:rb[3];
            us4 v[8];
            #pragma unroll
            for (int j = 0; j < 8; j++)
                v[j] = *(const us4*)(kvb + (size_t)rows[j] * HD + d0);
            #pragma unroll
            for (int j = 0; j < 8; j++)
                *(us4*)&g[kg * 8 + j][d0] = v[j];
            #pragma unroll
            for (int dd = 0; dd < 4; dd++) {          // 8-key packs -> b128 writes
                us8 w;
                w[0]=v[0][dd]; w[1]=v[1][dd]; w[2]=v[2][dd]; w[3]=v[3][dd];
                w[4]=v[4][dd]; w[5]=v[5][dd]; w[6]=v[6][dd]; w[7]=v[7][dd];
                *(us8*)&gt[d0 + dd][kg * 8] = w;
            }
        }
        // phase B: dims 512..575 (rope part), g only
        if (tid < 64) {
            int kg = tid >> 4;
            int d0 = 512 + (tid & 15) * 4;
            const int* ip = tkrow + it * KT + kg * 8;
            #pragma unroll
            for (int j = 0; j < 8; j++) {
                int raw = ip[j];
                int row = raw < 0 ? 0 : raw;
                *(us4*)&g[kg * 8 + j][d0] = *(const us4*)(kvb + (size_t)row * HD + d0);
            }
        }
        if (tid < KT) {
            int raw = tkrow[it * KT + tid];
            bias[tid] = raw < 0 ? -__builtin_inff() : 0.0f;
        }
        __syncthreads();

        // ---- S = Q * G^T : this wave's 16x16 tile [mtile, ntile] ----
        {
            f32x4 sacc = zero;
            #pragma unroll
            for (int ks = 0; ks < KSTEPS; ks++) {
                half8 bf = *(const half8*)&g[ntile * 16 + l16][ks * 32 + quad * 8];
                sacc = __builtin_amdgcn_mfma_f32_16x16x32_f16(qf[ks], bf, sacc, 0, 0, 0);
            }
            int hh = mtile * 16 + quad * 4;           // C-layout: row = quad*4+reg
            int kk = ntile * 16 + l16;                //           col = lane&15
            sbuf[hh + 0][kk] = sacc[0];
            sbuf[hh + 1][kk] = sacc[1];
            sbuf[hh + 2][kk] = sacc[2];
            sbuf[hh + 3][kk] = sacc[3];
        }
        __syncthreads();

        // ---- online softmax: 8 threads per head, 4 keys each ----
        {
            int h  = tid >> 3;
            int j  = tid & 7;
            int k0 = j * 4;
            f32x4 sv = *(const f32x4*)&sbuf[h][k0];
            f32x4 bv = *(const f32x4*)&bias[k0];
            float v0 = sv[0] * SCALE + bv[0];
            float v1 = sv[1] * SCALE + bv[1];
            float v2 = sv[2] * SCALE + bv[2];
            float v3 = sv[3] * SCALE + bv[3];
            float tm = fmaxf(fmaxf(v0, v1), fmaxf(v2, v3));
            tm = fmaxf(tm, __shfl_xor(tm, 1));
            tm = fmaxf(tm, __shfl_xor(tm, 2));
            tm = fmaxf(tm, __shfl_xor(tm, 4));
            float m_old = mrun[h];
            float m_new = fmaxf(m_old, tm);           // m_old >= sink: always finite
            float alpha = __expf(m_old - m_new);
            float p0 = __expf(v0 - m_new);            // -inf input -> 0, safe
            float p1 = __expf(v1 - m_new);
            float p2 = __expf(v2 - m_new);
            float p3 = __expf(v3 - m_new);
            float ps = (p0 + p1) + (p2 + p3);
            ps += __shfl_xor(ps, 1);
            ps += __shfl_xor(ps, 2);
            ps += __shfl_xor(ps, 4);
            if (j == 0) {
                mrun[h] = m_new;
                lrun[h] = lrun[h] * alpha + ps;
                arun[h] = alpha;
            }
            us4 pw;
            pw[0]=f2h(p0); pw[1]=f2h(p1); pw[2]=f2h(p2); pw[3]=f2h(p3);
            *(us4*)&pbuf[h][k0] = pw;
        }
        __syncthreads();

        // ---- PV: rescale accumulators by alpha, then accumulate P * Gv ----
        {
            half8 pa[4], vb[4];
            #pragma unroll
            for (int mt = 0; mt < 4; mt++)
                pa[mt] = *(const half8*)&pbuf[mt * 16 + l16][quad * 8];
            #pragma unroll
            for (int nt = 0; nt < 4; nt++)
                vb[nt] = *(const half8*)&gt[col0 + nt * 16 + l16][quad * 8];
            #pragma unroll
            for (int mt = 0; mt < 4; mt++) {
                f32x4 al = *(const f32x4*)&arun[mt * 16 + quad * 4];
                #pragma unroll
                for (int nt = 0; nt < 4; nt++) {
                    acc[mt][nt] *= al;
                    acc[mt][nt] = __builtin_amdgcn_mfma_f32_16x16x32_f16(pa[mt], vb[nt], acc[mt][nt], 0, 0, 0);
                }
            }
        }
        __syncthreads();  // doubles as the safe-to-overwrite barrier for next staging
    }

    // ---- epilogue: divide by denom, store ----
    #pragma unroll
    for (int mt = 0; mt < 4; mt++) {
        f32x4 lv = *(const f32x4*)&lrun[mt * 16 + quad * 4];
        f32x4 linv;
        linv[0] = 1.0f / lv[0]; linv[1] = 1.0f / lv[1];
        linv[2] = 1.0f / lv[2]; linv[3] = 1.0f / lv[3];
        #pragma unroll
        for (int nt = 0; nt < 4; nt++) {
            int vcol = col0 + nt * 16 + l16;
            f32x4 r = acc[mt][nt] * linv;
            #pragma unroll
            for (int rr = 0; rr < 4; rr++) {
                int head = mt * 16 + quad * 4 + rr;
                out[((size_t)t * NH + head) * DVAL + vcol] = r[rr];
            }
        }
    }
}

extern "C" void kernel_launch(void* const* d_in, const int* in_sizes, int n_in,
                              void* d_out, int out_size, void* d_ws, size_t ws_size,
                              hipStream_t stream) {
    const float* q    = (const float*)d_in[0];   // [512,64,576]
    const float* kv   = (const float*)d_in[1];   // [8192,576]
    const int*   topk = (const int*)d_in[2];     // [512,1024]
    const float* sink = (const float*)d_in[3];   // [64]
    float* out = (float*)d_out;                  // [512,64,512]
    unsigned short* kvb = (unsigned short*)d_ws; // fp16 kv cache, 9,437,184 B

    cvt_kv_f16<<<NKV * HD / (256 * 8), 256, 0, stream>>>(kv, kvb);
    mla_sparse_kernel<<<T_TOK, 512, 0, stream>>>(q, topk, sink, kvb, out);
}